// Round 12
// baseline (1277.204 us; speedup 1.0000x reference)
//
#include <hip/hip_runtime.h>
#include <stdint.h>

#define DB   8
#define DC   64
#define DLX  256
#define DLY  256
#define DD   768
#define DH0  1536
#define DH1  768
#define NBC  (DB*DC)        // 512
#define NTOK (NBC*DLX)      // 131072
#define TAU  0.25f

typedef float f32x4 __attribute__((ext_vector_type(4)));
typedef _Float16 f16x8 __attribute__((ext_vector_type(8)));
typedef _Float16 f16x4 __attribute__((ext_vector_type(4)));

// fast softplus via hw exp2/log2
__device__ __forceinline__ float softplusf(float x){
  float t = __builtin_amdgcn_exp2f(-fabsf(x) * 1.44269504f);
  return fmaxf(x, 0.0f) + 0.69314718f * __builtin_amdgcn_logf(1.0f + t);
}

// async global->LDS, 16B per lane; lds base wave-uniform (linear dest)
__device__ __forceinline__ void gload_lds16(const void* g, void* l){
  __builtin_amdgcn_global_load_lds((const __attribute__((address_space(1))) void*)g,
                                   (__attribute__((address_space(3))) void*)l,
                                   16, 0, 0);
}

// ---------------- fp32 -> f16 conversion (strided submatrix) ----------------
__global__ __launch_bounds__(256) void k_cvt16(const float* __restrict__ src, int ld, int off,
                                               int rows, int cols, _Float16* __restrict__ dst){
  int total = rows * (cols >> 3);
  for (int idx = blockIdx.x * 256 + threadIdx.x; idx < total; idx += gridDim.x * 256){
    int r = idx / (cols >> 3), c8 = (idx % (cols >> 3)) * 8;
    const float* s = src + (size_t)r * ld + off + c8;
    float4 f0 = *(const float4*)s, f1 = *(const float4*)(s + 4);
    f16x8 v;
    v[0]=(_Float16)f0.x; v[1]=(_Float16)f0.y; v[2]=(_Float16)f0.z; v[3]=(_Float16)f0.w;
    v[4]=(_Float16)f1.x; v[5]=(_Float16)f1.y; v[6]=(_Float16)f1.z; v[7]=(_Float16)f1.w;
    *(f16x8*)(dst + (size_t)r * cols + c8) = v;
  }
}

// ---------------- scores: f16 MFMA + exact fp32 argmax fixup -> widx (R8 form) ----------------
__global__ __launch_bounds__(1024, 1) void k_scores3(const _Float16* __restrict__ xs16,
                                                     const _Float16* __restrict__ ys16,
                                                     const float* __restrict__ xs,
                                                     const float* __restrict__ ys,
                                                     int* __restrict__ widx){
  const int bc = blockIdx.y, b = bc >> 6;
  const int x0 = blockIdx.x * 128;
  const float* X = xs + ((size_t)b * DLX + x0) * DD;
  const float* Y = ys + (size_t)bc * DLY * DD;
  __shared__ __align__(16) _Float16 As[128 * 32];
  __shared__ __align__(16) _Float16 Bs[256 * 32];
  __shared__ float rmx[128][4];
  __shared__ float gm[128];
  __shared__ unsigned short cand[128][8];
  __shared__ int ccnt[128];
  const int tid = threadIdx.x;
  const int l = tid & 63, w = tid >> 6;     // 16 waves
  const int wr = w >> 2, wc = w & 3;        // wave tile 32x64
  const int lrow = l & 15, lg = l >> 4;
  const int kq = (lg ^ (lrow & 3)) * 8;
  const int srow = l >> 2;
  const int kg = (((l & 3) ^ ((l >> 2) & 3))) * 8;
  const _Float16* srcB = ys16 + ((size_t)bc * DLY + w*16 + srow) * DD + kg;
  const _Float16* srcA = xs16 + ((size_t)b * DLX + x0 + (w & 7)*16 + srow) * DD + kg;

  f32x4 acc[2][4];
  #pragma unroll
  for (int i = 0; i < 2; i++)
    #pragma unroll
    for (int j = 0; j < 4; j++) acc[i][j] = (f32x4){0.f,0.f,0.f,0.f};

  for (int k0 = 0; k0 < DD; k0 += 32){
    __syncthreads();
    gload_lds16(srcB + k0, Bs + w*512);
    if (w < 8) gload_lds16(srcA + k0, As + w*512);
    __syncthreads();
    f16x8 af[2], bf[4];
    #pragma unroll
    for (int i = 0; i < 2; i++)
      af[i] = *(const f16x8*)&As[(wr*32 + i*16 + lrow)*32 + kq];
    #pragma unroll
    for (int j = 0; j < 4; j++)
      bf[j] = *(const f16x8*)&Bs[(wc*64 + j*16 + lrow)*32 + kq];
    #pragma unroll
    for (int i = 0; i < 2; i++)
      #pragma unroll
      for (int j = 0; j < 4; j++)
        acc[i][j] = __builtin_amdgcn_mfma_f32_16x16x32_f16(af[i], bf[j], acc[i][j], 0, 0, 0);
  }

  #pragma unroll
  for (int i = 0; i < 2; i++)
    #pragma unroll
    for (int r = 0; r < 4; r++){
      float m = fmaxf(fmaxf(acc[i][0][r], acc[i][1][r]), fmaxf(acc[i][2][r], acc[i][3][r]));
      m = fmaxf(m, __shfl_xor(m, 1));
      m = fmaxf(m, __shfl_xor(m, 2));
      m = fmaxf(m, __shfl_xor(m, 4));
      m = fmaxf(m, __shfl_xor(m, 8));
      if (lrow == 0) rmx[wr*32 + i*16 + lg*4 + r][wc] = m;
    }
  __syncthreads();
  if (tid < 128){
    gm[tid] = fmaxf(fmaxf(rmx[tid][0], rmx[tid][1]), fmaxf(rmx[tid][2], rmx[tid][3]));
    ccnt[tid] = 0;
  }
  __syncthreads();
  #pragma unroll
  for (int i = 0; i < 2; i++)
    #pragma unroll
    for (int r = 0; r < 4; r++){
      int t = wr*32 + i*16 + lg*4 + r;
      float thr = gm[t] - TAU;
      #pragma unroll
      for (int j = 0; j < 4; j++){
        float s = acc[i][j][r];
        if (s >= thr){
          int p = atomicAdd(&ccnt[t], 1);
          if (p < 8) cand[t][p] = (unsigned short)(wc*64 + j*16 + lrow);
        }
      }
    }
  __syncthreads();
  for (int it = 0; it < 8; it++){
    int t = w * 8 + it;
    int cnt = ccnt[t];
    int by;
    if (cnt == 1){
      by = cand[t][0];
    } else {
      const float* xr = X + (size_t)t * DD;
      float best = -1e30f; int besty = 0;
      int n = (cnt <= 8) ? cnt : 256;
      for (int p = 0; p < n; p++){
        int c = (cnt <= 8) ? (int)cand[t][p] : p;
        const float* yr = Y + (size_t)c * DD;
        float s = 0.f;
        #pragma unroll
        for (int q = 0; q < 3; q++){
          float4 xv = *(const float4*)(xr + l*12 + q*4);
          float4 yv = *(const float4*)(yr + l*12 + q*4);
          s += xv.x*yv.x + xv.y*yv.y + xv.z*yv.z + xv.w*yv.w;
        }
        s += __shfl_xor(s, 1);  s += __shfl_xor(s, 2);  s += __shfl_xor(s, 4);
        s += __shfl_xor(s, 8);  s += __shfl_xor(s, 16); s += __shfl_xor(s, 32);
        if (s > best || (s == best && c < besty)){ best = s; besty = c; }
      }
      by = besty;
    }
    if (l == 0) widx[(size_t)bc * DLX + x0 + t] = by;
  }
}

// ---------------- 128x256 f16 MFMA GEMM, 8 waves, BK=64, dbuf + counted vmcnt ----------------
// Per K-step: issue next-buf loads -> s_waitcnt vmcnt(6) -> s_barrier -> ds_read+MFMA -> s_barrier.
// Two barriers bound wave skew to <1 buffer (no overwrite race); vmcnt never drains to 0 mid-loop.
// LDS: S[2][24576] halves = 96 KB (A at 0..8191, B at 8192.. per buffer).
// MODE 0: X0h = f16(xs16 @ W0x^T + b0)               (grid 6 x 16)
// MODE 1: H0 = softplus(ys16[widx] @ W0y^T + X0h)    (grid 6 x 1024)
// MODE 2: spart = softplus(H0 @ W1^T + b1) . w2      (grid 3 x 1024)
template<int MODE>
__global__ __launch_bounds__(512) void k_gemm16(const _Float16* __restrict__ A,
        unsigned bdelta,                       // (B - A) in halves
        const int* __restrict__ widx,
        const _Float16* __restrict__ X0h,
        const float* __restrict__ bias,
        const float* __restrict__ w2,
        float* __restrict__ outF,
        _Float16* __restrict__ outH){
  constexpr int K = (MODE == 2) ? DH0 : DD;
  constexpr unsigned BUFH = 24576;                  // halves per buffer
  __shared__ __align__(16) _Float16 S[2][BUFH];     // 96 KB
  const int tid = threadIdx.x;
  const int gx = gridDim.x, nwg = gx * gridDim.y;
  int lin = blockIdx.x + gx * blockIdx.y;
  int swz = (lin & 7) * (nwg >> 3) + (lin >> 3);   // bijective (nwg % 8 == 0)
  const int n0  = (swz % gx) * 256;
  const int by  = swz / gx;
  const int rt0 = by * 128;
  const int l = tid & 63, w = tid >> 6;            // 8 waves
  const int wr = w >> 2, wc = w & 3;               // wave tile 64m x 64n
  const int lrow = l & 15, lg = l >> 4;

  int bc = 0, xb = 0, b = 0;
  if constexpr (MODE == 1){ bc = by >> 1; xb = (by & 1) * 128; b = bc >> 6; }

  // staging: 48 1KB-units (0..15 = A 8-row groups, 16..47 = B), 6 per wave.
  // lane l -> in-unit row (l>>3), dest slot (l&7); source slot (l&7)^(row&7).
  const int urow = l >> 3;
  const int uslot = (l & 7) ^ (urow & 7);          // pre-swizzled source slot
  unsigned goff[6];                                // halves offset from A base
  _Float16* ldst[6];                               // dest in buffer 0
  #pragma unroll
  for (int i = 0; i < 6; i++){
    int u = w*6 + i;
    if (u < 16){
      int row = u*8 + urow;
      unsigned aoff;
      if constexpr (MODE == 1){
        int yi = widx[bc * DLX + xb + row];
        aoff = (unsigned)((bc * DLY + yi) * DD);
      } else {
        aoff = (unsigned)((rt0 + row) * K);
      }
      goff[i] = aoff + uslot*8;
      ldst[i] = &S[0][0] + u*512;
    } else {
      int row = (u - 16)*8 + urow;
      goff[i] = bdelta + (unsigned)((n0 + row) * K) + uslot*8;
      ldst[i] = &S[0][0] + 8192 + (u - 16)*512;
    }
  }

  f32x4 acc[4][4];
  #pragma unroll
  for (int i = 0; i < 4; i++)
    #pragma unroll
    for (int j = 0; j < 4; j++) acc[i][j] = (f32x4){0.f,0.f,0.f,0.f};

  // prologue: stage K-step 0 into buffer 0
  #pragma unroll
  for (int i = 0; i < 6; i++) gload_lds16(A + (size_t)goff[i], ldst[i]);

  unsigned lo = 0;
  for (int k0 = 0; k0 < K; k0 += 64){
    if (k0 + 64 < K){
      #pragma unroll
      for (int i = 0; i < 6; i++)
        gload_lds16(A + (size_t)(goff[i] + (unsigned)(k0 + 64)), ldst[i] + (lo ^ BUFH));
      asm volatile("s_waitcnt vmcnt(6)" ::: "memory");
    } else {
      asm volatile("s_waitcnt vmcnt(0)" ::: "memory");
    }
    __builtin_amdgcn_s_barrier();
    const _Float16* Sb = &S[0][0] + lo;
    #pragma unroll
    for (int kh = 0; kh < 2; kh++){
      const int rc = ((kh*4 + lg) ^ (lrow & 7)) * 8;   // swizzled read col (halves)
      f16x8 af[4], bf[4];
      #pragma unroll
      for (int i = 0; i < 4; i++){
        af[i] = *(const f16x8*)&Sb[(wr*64 + i*16 + lrow)*64 + rc];
        bf[i] = *(const f16x8*)&Sb[8192 + (wc*64 + i*16 + lrow)*64 + rc];
      }
      #pragma unroll
      for (int i = 0; i < 4; i++)
        #pragma unroll
        for (int j = 0; j < 4; j++)
          acc[i][j] = __builtin_amdgcn_mfma_f32_16x16x32_f16(af[i], bf[j], acc[i][j], 0, 0, 0);
    }
    __builtin_amdgcn_s_barrier();
    lo ^= BUFH;
  }

  if constexpr (MODE == 0){
    #pragma unroll
    for (int mi = 0; mi < 4; mi++)
      #pragma unroll
      for (int ni = 0; ni < 4; ni++){
        int n = n0 + wc*64 + ni*16 + lrow;
        float bv = bias[n];
        #pragma unroll
        for (int r = 0; r < 4; r++){
          int m = wr*64 + mi*16 + lg*4 + r;
          outH[(size_t)(rt0 + m) * DH0 + n] = (_Float16)(acc[mi][ni][r] + bv);
        }
      }
  } else if constexpr (MODE == 1){
    #pragma unroll
    for (int mi = 0; mi < 4; mi++)
      #pragma unroll
      for (int ni = 0; ni < 4; ni++){
        int n = n0 + wc*64 + ni*16 + lrow;
        #pragma unroll
        for (int r = 0; r < 4; r++){
          int m = wr*64 + mi*16 + lg*4 + r;
          float x0v = (float)X0h[((size_t)b * DLX + xb + m) * DH0 + n];
          float v = softplusf(acc[mi][ni][r] + x0v);
          outH[(size_t)(rt0 + m) * DH0 + n] = (_Float16)v;
        }
      }
  } else {
    float p[4][4];
    #pragma unroll
    for (int mi = 0; mi < 4; mi++)
      #pragma unroll
      for (int r = 0; r < 4; r++) p[mi][r] = 0.f;
    #pragma unroll
    for (int ni = 0; ni < 4; ni++){
      int n = n0 + wc*64 + ni*16 + lrow;
      float b1v = bias[n], w2v = w2[n];
      #pragma unroll
      for (int mi = 0; mi < 4; mi++)
        #pragma unroll
        for (int r = 0; r < 4; r++)
          p[mi][r] += softplusf(acc[mi][ni][r] + b1v) * w2v;
    }
    const int nb = (int)(swz % gx);
    #pragma unroll
    for (int mi = 0; mi < 4; mi++)
      #pragma unroll
      for (int r = 0; r < 4; r++){
        float s = p[mi][r];
        s += __shfl_xor(s, 1);
        s += __shfl_xor(s, 2);
        s += __shfl_xor(s, 4);
        s += __shfl_xor(s, 8);
        if (lrow == 0){
          size_t t = (size_t)rt0 + wr*64 + mi*16 + lg*4 + r;
          outF[t * 12 + nb*4 + wc] = s;
        }
      }
  }
}

// ---------------- final reduce ----------------
__global__ __launch_bounds__(256) void k_reduce(const float* __restrict__ spart,
                                                const float* __restrict__ b2,
                                                float* __restrict__ out){
  int bc = blockIdx.x, tid = threadIdx.x;
  const float* p = spart + ((size_t)bc * DLX + tid) * 12;
  float s = 0.0f;
  #pragma unroll
  for (int j = 0; j < 12; j++) s += p[j];
  __shared__ float red[256];
  red[tid] = s;
  __syncthreads();
  for (int off = 128; off > 0; off >>= 1){
    if (tid < off) red[tid] += red[tid + off];
    __syncthreads();
  }
  if (tid == 0) out[bc] = red[0] + 256.0f * b2[0];
}

extern "C" void kernel_launch(void* const* d_in, const int* in_sizes, int n_in,
                              void* d_out, int out_size, void* d_ws, size_t ws_size,
                              hipStream_t stream){
  const float* xs = (const float*)d_in[0];
  const float* ys = (const float*)d_in[1];
  const float* W0 = (const float*)d_in[2];
  const float* b0 = (const float*)d_in[3];
  const float* W1 = (const float*)d_in[4];
  const float* b1 = (const float*)d_in[5];
  const float* W2 = (const float*)d_in[6];
  const float* b2 = (const float*)d_in[7];
  float* out = (float*)d_out;

  char* wsp = (char*)d_ws;
  size_t off = 0;
  auto alloc = [&](size_t bytes)->void*{
    void* p = wsp + off;
    off += (bytes + 255) & ~(size_t)255;
    return p;
  };
  // adjacency groups for 32-bit B-deltas: (ys16, W0yf), (xs16, W0xf), (H0, W1f)
  int* widx        = (int*)alloc((size_t)NTOK * 4);
  _Float16* ys16   = (_Float16*)alloc((size_t)NBC * DLY * DD * 2);   // 201 MB
  _Float16* W0yf   = (_Float16*)alloc((size_t)DH0 * DD * 2);
  _Float16* xs16   = (_Float16*)alloc((size_t)DB * DLX * DD * 2);
  _Float16* W0xf   = (_Float16*)alloc((size_t)DH0 * DD * 2);
  _Float16* X0h    = (_Float16*)alloc((size_t)DB * DLX * DH0 * 2);   // 6.3 MB
  float* spart     = (float*)alloc((size_t)NTOK * 12 * 4);           // 6.3 MB
  _Float16* H0     = (_Float16*)alloc((size_t)NTOK * DH0 * 2);       // 402 MB
  _Float16* W1f    = (_Float16*)alloc((size_t)DH1 * DH0 * 2);

  unsigned d0 = (unsigned)(W0xf - xs16);
  unsigned d1 = (unsigned)(W0yf - ys16);
  unsigned d2 = (unsigned)(W1f - H0);

  k_cvt16<<<dim3(576),  256, 0, stream>>>(W0, DH0, 0,  DH0, DD, W0xf);
  k_cvt16<<<dim3(576),  256, 0, stream>>>(W0, DH0, DD, DH0, DD, W0yf);
  k_cvt16<<<dim3(576),  256, 0, stream>>>(W1, DH0, 0,  DH1, DH0, W1f);
  k_cvt16<<<dim3(768),  256, 0, stream>>>(xs, DD, 0, DB*DLX, DD, xs16);
  k_cvt16<<<dim3(4096), 256, 0, stream>>>(ys, DD, 0, NBC*DLY, DD, ys16);
  k_scores3<<<dim3(2, NBC), 1024, 0, stream>>>(xs16, ys16, xs, ys, widx);
  k_gemm16<0><<<dim3(6, 16),   512, 0, stream>>>(xs16, d0, nullptr, nullptr, b0, nullptr, nullptr, X0h);
  k_gemm16<1><<<dim3(6, 1024), 512, 0, stream>>>(ys16, d1, widx, X0h, nullptr, nullptr, nullptr, H0);
  k_gemm16<2><<<dim3(3, 1024), 512, 0, stream>>>(H0, d2, nullptr, nullptr, b1, W2, spart, nullptr);
  k_reduce<<<NBC, 256, 0, stream>>>(spart, b2, out);
}

// Round 13
// 921.376 us; speedup vs baseline: 1.3862x; 1.3862x over previous
//
#include <hip/hip_runtime.h>
#include <stdint.h>

#define DB   8
#define DC   64
#define DLX  256
#define DLY  256
#define DD   768
#define DH0  1536
#define DH1  768
#define NBC  (DB*DC)        // 512
#define NTOK (NBC*DLX)      // 131072
#define TAU  0.25f

typedef float f32x4 __attribute__((ext_vector_type(4)));
typedef _Float16 f16x8 __attribute__((ext_vector_type(8)));
typedef _Float16 f16x4 __attribute__((ext_vector_type(4)));

// fast softplus via hw exp2/log2
__device__ __forceinline__ float softplusf(float x){
  float t = __builtin_amdgcn_exp2f(-fabsf(x) * 1.44269504f);
  return fmaxf(x, 0.0f) + 0.69314718f * __builtin_amdgcn_logf(1.0f + t);
}

// async global->LDS, 16B per lane; lds base wave-uniform (linear dest)
__device__ __forceinline__ void gload_lds16(const void* g, void* l){
  __builtin_amdgcn_global_load_lds((const __attribute__((address_space(1))) void*)g,
                                   (__attribute__((address_space(3))) void*)l,
                                   16, 0, 0);
}

// ---------------- fp32 -> f16 conversion (strided submatrix; weights + xs only) ----------------
__global__ __launch_bounds__(256) void k_cvt16(const float* __restrict__ src, int ld, int off,
                                               int rows, int cols, _Float16* __restrict__ dst){
  int total = rows * (cols >> 3);
  for (int idx = blockIdx.x * 256 + threadIdx.x; idx < total; idx += gridDim.x * 256){
    int r = idx / (cols >> 3), c8 = (idx % (cols >> 3)) * 8;
    const float* s = src + (size_t)r * ld + off + c8;
    float4 f0 = *(const float4*)s, f1 = *(const float4*)(s + 4);
    f16x8 v;
    v[0]=(_Float16)f0.x; v[1]=(_Float16)f0.y; v[2]=(_Float16)f0.z; v[3]=(_Float16)f0.w;
    v[4]=(_Float16)f1.x; v[5]=(_Float16)f1.y; v[6]=(_Float16)f1.z; v[7]=(_Float16)f1.w;
    *(f16x8*)(dst + (size_t)r * cols + c8) = v;
  }
}

// ---------------- scores + fused ys->f16: one block per (b,c), 1024 threads ----------------
// A (xs16) staged via gload_lds; B (ys fp32) reg-staged with convert, written to LDS + ys16.
// f16 MFMA scores -> exact fp32 argmax fixup -> widx.
__global__ __launch_bounds__(1024, 2) void k_scores4(const _Float16* __restrict__ xs16,
                                                     const float* __restrict__ ys,
                                                     const float* __restrict__ xs,
                                                     _Float16* __restrict__ ys16,
                                                     int* __restrict__ widx){
  const int bc = blockIdx.x, b = bc >> 6;
  const float* Y = ys + (size_t)bc * DLY * DD;
  __shared__ __align__(16) _Float16 As[256 * 32];   // 16 KB
  __shared__ __align__(16) _Float16 Bs[256 * 32];   // 16 KB
  __shared__ float rmx[256][4];
  __shared__ float gm[256];
  __shared__ unsigned short cand[256][8];
  __shared__ int ccnt[256];
  const int tid = threadIdx.x;
  const int l = tid & 63, w = tid >> 6;     // 16 waves
  const int wr = w >> 2, wc = w & 3;        // wave tile 64m x 64n
  const int lrow = l & 15, lg = l >> 4;
  const int kq = (lg ^ (lrow & 3)) * 8;     // swizzled read col (halves)
  // A staging: wave w stages rows w*16..w*16+15 (xs16), pre-swizzled source col
  const int kg = (((l & 3) ^ ((l >> 2) & 3))) * 8;
  const _Float16* srcA = xs16 + ((size_t)b * DLX + w*16 + (l >> 2)) * DD + kg;
  // B staging: thread -> row r, 8 f32 cols; LDS slot swizzled, global write linear
  const int r = tid >> 2, c8 = (tid & 3) * 8;
  const float* srcB = Y + (size_t)r * DD + c8;
  _Float16* ydst = ys16 + ((size_t)bc * DLY + r) * DD + c8;
  const int bslot = (((tid & 3) ^ (r & 3))) * 8;

  f32x4 acc[4][4];
  #pragma unroll
  for (int i = 0; i < 4; i++)
    #pragma unroll
    for (int j = 0; j < 4; j++) acc[i][j] = (f32x4){0.f,0.f,0.f,0.f};

  for (int k0 = 0; k0 < DD; k0 += 32){
    float4 f0 = *(const float4*)(srcB + k0);
    float4 f1 = *(const float4*)(srcB + k0 + 4);
    f16x8 hv;
    hv[0]=(_Float16)f0.x; hv[1]=(_Float16)f0.y; hv[2]=(_Float16)f0.z; hv[3]=(_Float16)f0.w;
    hv[4]=(_Float16)f1.x; hv[5]=(_Float16)f1.y; hv[6]=(_Float16)f1.z; hv[7]=(_Float16)f1.w;
    __syncthreads();
    gload_lds16(srcA + k0, As + w*512);
    *(f16x8*)&Bs[r*32 + bslot] = hv;
    *(f16x8*)(ydst + k0) = hv;
    __syncthreads();
    f16x8 af[4], bf[4];
    #pragma unroll
    for (int i = 0; i < 4; i++){
      af[i] = *(const f16x8*)&As[(wr*64 + i*16 + lrow)*32 + kq];
      bf[i] = *(const f16x8*)&Bs[(wc*64 + i*16 + lrow)*32 + kq];
    }
    #pragma unroll
    for (int i = 0; i < 4; i++)
      #pragma unroll
      for (int j = 0; j < 4; j++)
        acc[i][j] = __builtin_amdgcn_mfma_f32_16x16x32_f16(af[i], bf[j], acc[i][j], 0, 0, 0);
  }

  // per-token noisy max over this wave's 64 cols, then block-wide
  #pragma unroll
  for (int i = 0; i < 4; i++)
    #pragma unroll
    for (int r2 = 0; r2 < 4; r2++){
      float m = fmaxf(fmaxf(acc[i][0][r2], acc[i][1][r2]), fmaxf(acc[i][2][r2], acc[i][3][r2]));
      m = fmaxf(m, __shfl_xor(m, 1));
      m = fmaxf(m, __shfl_xor(m, 2));
      m = fmaxf(m, __shfl_xor(m, 4));
      m = fmaxf(m, __shfl_xor(m, 8));
      if (lrow == 0) rmx[wr*64 + i*16 + lg*4 + r2][wc] = m;
    }
  __syncthreads();
  if (tid < 256){
    gm[tid] = fmaxf(fmaxf(rmx[tid][0], rmx[tid][1]), fmaxf(rmx[tid][2], rmx[tid][3]));
    ccnt[tid] = 0;
  }
  __syncthreads();
  #pragma unroll
  for (int i = 0; i < 4; i++)
    #pragma unroll
    for (int r2 = 0; r2 < 4; r2++){
      int t = wr*64 + i*16 + lg*4 + r2;
      float thr = gm[t] - TAU;
      #pragma unroll
      for (int j = 0; j < 4; j++){
        float s = acc[i][j][r2];
        if (s >= thr){
          int p = atomicAdd(&ccnt[t], 1);
          if (p < 8) cand[t][p] = (unsigned short)(wc*64 + j*16 + lrow);
        }
      }
    }
  __syncthreads();
  // resolve: wave w handles tokens w*16..w*16+15; cnt>1 -> exact fp32 dots
  for (int it = 0; it < 16; it++){
    int t = w * 16 + it;
    int cnt = ccnt[t];
    int by;
    if (cnt == 1){
      by = cand[t][0];
    } else {
      const float* xr = xs + ((size_t)b * DLX + t) * DD;
      float best = -1e30f; int besty = 0;
      int n = (cnt <= 8) ? cnt : 256;
      for (int p = 0; p < n; p++){
        int c = (cnt <= 8) ? (int)cand[t][p] : p;
        const float* yr = Y + (size_t)c * DD;
        float s = 0.f;
        #pragma unroll
        for (int q = 0; q < 3; q++){
          float4 xv = *(const float4*)(xr + l*12 + q*4);
          float4 yv = *(const float4*)(yr + l*12 + q*4);
          s += xv.x*yv.x + xv.y*yv.y + xv.z*yv.z + xv.w*yv.w;
        }
        s += __shfl_xor(s, 1);  s += __shfl_xor(s, 2);  s += __shfl_xor(s, 4);
        s += __shfl_xor(s, 8);  s += __shfl_xor(s, 16); s += __shfl_xor(s, 32);
        if (s > best || (s == best && c < besty)){ best = s; besty = c; }
      }
      by = besty;
    }
    if (l == 0) widx[(size_t)bc * DLX + t] = by;
  }
}

// ---------------- 128x256 f16 MFMA GEMM, 8 waves, BK=64, XCD-swizzled (R11, verified) ----------------
// B reached via 32-bit delta from A base (adjacent ws allocs) to keep VGPR low.
// LDS rows are 128B: slot-XOR swizzle s^=(row&7) on BOTH source and read (conflict-free, R11: 0).
// MODE 0: X0h = f16(xs16 @ W0x^T + b0)               (grid 6 x 16)
// MODE 1: H0 = softplus(ys16[widx] @ W0y^T + X0h)    (grid 6 x 1024)
// MODE 2: spart = softplus(H0 @ W1^T + b1) . w2      (grid 3 x 1024)
template<int MODE>
__global__ __launch_bounds__(512) void k_gemm16(const _Float16* __restrict__ A,
        unsigned bdelta,                       // (B - A) in halves
        const int* __restrict__ widx,
        const _Float16* __restrict__ X0h,
        const float* __restrict__ bias,
        const float* __restrict__ w2,
        float* __restrict__ outF,
        _Float16* __restrict__ outH){
  constexpr int K = (MODE == 2) ? DH0 : DD;
  __shared__ __align__(16) _Float16 As[128 * 64];   // 16 KB
  __shared__ __align__(16) _Float16 Bs[256 * 64];   // 32 KB
  const int tid = threadIdx.x;
  const int gx = gridDim.x, nwg = gx * gridDim.y;
  int lin = blockIdx.x + gx * blockIdx.y;
  int swz = (lin & 7) * (nwg >> 3) + (lin >> 3);   // bijective (nwg % 8 == 0)
  const int n0  = (swz % gx) * 256;
  const int by  = swz / gx;
  const int rt0 = by * 128;
  const int l = tid & 63, w = tid >> 6;            // 8 waves
  const int wr = w >> 2, wc = w & 3;               // wave tile 64m x 64n
  const int lrow = l & 15, lg = l >> 4;

  int bc = 0, xb = 0, b = 0;
  if constexpr (MODE == 1){ bc = by >> 1; xb = (by & 1) * 128; b = bc >> 6; }

  // staging: 48 1KB-units (0..15 = A 8-row groups, 16..47 = B), 6 per wave.
  // lane l -> in-unit row (l>>3), dest slot (l&7); source slot (l&7)^(row&7).
  const int urow = l >> 3;
  const int uslot = (l & 7) ^ (urow & 7);          // pre-swizzled source slot
  unsigned goff[6];                                // halves offset from A base
  _Float16* ldst[6];
  #pragma unroll
  for (int i = 0; i < 6; i++){
    int u = w*6 + i;
    if (u < 16){
      int row = u*8 + urow;
      unsigned aoff;
      if constexpr (MODE == 1){
        int yi = widx[bc * DLX + xb + row];
        aoff = (unsigned)((bc * DLY + yi) * DD);
      } else {
        aoff = (unsigned)((rt0 + row) * K);
      }
      goff[i] = aoff + uslot*8;
      ldst[i] = (_Float16*)As + u*512;
    } else {
      int row = (u - 16)*8 + urow;
      goff[i] = bdelta + (unsigned)((n0 + row) * K) + uslot*8;
      ldst[i] = (_Float16*)Bs + (u - 16)*512;
    }
  }

  f32x4 acc[4][4];
  #pragma unroll
  for (int i = 0; i < 4; i++)
    #pragma unroll
    for (int j = 0; j < 4; j++) acc[i][j] = (f32x4){0.f,0.f,0.f,0.f};

  for (int k0 = 0; k0 < K; k0 += 64){
    __syncthreads();
    #pragma unroll
    for (int i = 0; i < 6; i++)
      gload_lds16(A + (size_t)(goff[i] + (unsigned)k0), ldst[i]);
    __syncthreads();
    #pragma unroll
    for (int kh = 0; kh < 2; kh++){
      const int rc = ((kh*4 + lg) ^ (lrow & 7)) * 8;   // swizzled read col (halves)
      f16x8 af[4], bf[4];
      #pragma unroll
      for (int i = 0; i < 4; i++){
        af[i] = *(const f16x8*)&As[(wr*64 + i*16 + lrow)*64 + rc];
        bf[i] = *(const f16x8*)&Bs[(wc*64 + i*16 + lrow)*64 + rc];
      }
      #pragma unroll
      for (int i = 0; i < 4; i++)
        #pragma unroll
        for (int j = 0; j < 4; j++)
          acc[i][j] = __builtin_amdgcn_mfma_f32_16x16x32_f16(af[i], bf[j], acc[i][j], 0, 0, 0);
    }
  }

  if constexpr (MODE == 0){
    #pragma unroll
    for (int mi = 0; mi < 4; mi++)
      #pragma unroll
      for (int ni = 0; ni < 4; ni++){
        int n = n0 + wc*64 + ni*16 + lrow;
        float bv = bias[n];
        #pragma unroll
        for (int r = 0; r < 4; r++){
          int m = wr*64 + mi*16 + lg*4 + r;
          outH[(size_t)(rt0 + m) * DH0 + n] = (_Float16)(acc[mi][ni][r] + bv);
        }
      }
  } else if constexpr (MODE == 1){
    #pragma unroll
    for (int mi = 0; mi < 4; mi++)
      #pragma unroll
      for (int ni = 0; ni < 4; ni++){
        int n = n0 + wc*64 + ni*16 + lrow;
        #pragma unroll
        for (int r = 0; r < 4; r++){
          int m = wr*64 + mi*16 + lg*4 + r;
          float x0v = (float)X0h[((size_t)b * DLX + xb + m) * DH0 + n];
          float v = softplusf(acc[mi][ni][r] + x0v);
          outH[(size_t)(rt0 + m) * DH0 + n] = (_Float16)v;
        }
      }
  } else {
    float p[4][4];
    #pragma unroll
    for (int mi = 0; mi < 4; mi++)
      #pragma unroll
      for (int r = 0; r < 4; r++) p[mi][r] = 0.f;
    #pragma unroll
    for (int ni = 0; ni < 4; ni++){
      int n = n0 + wc*64 + ni*16 + lrow;
      float b1v = bias[n], w2v = w2[n];
      #pragma unroll
      for (int mi = 0; mi < 4; mi++)
        #pragma unroll
        for (int r = 0; r < 4; r++)
          p[mi][r] += softplusf(acc[mi][ni][r] + b1v) * w2v;
    }
    const int nb = (int)(swz % gx);
    #pragma unroll
    for (int mi = 0; mi < 4; mi++)
      #pragma unroll
      for (int r = 0; r < 4; r++){
        float s = p[mi][r];
        s += __shfl_xor(s, 1);
        s += __shfl_xor(s, 2);
        s += __shfl_xor(s, 4);
        s += __shfl_xor(s, 8);
        if (lrow == 0){
          size_t t = (size_t)rt0 + wr*64 + mi*16 + lg*4 + r;
          outF[t * 12 + nb*4 + wc] = s;
        }
      }
  }
}

// ---------------- final reduce ----------------
__global__ __launch_bounds__(256) void k_reduce(const float* __restrict__ spart,
                                                const float* __restrict__ b2,
                                                float* __restrict__ out){
  int bc = blockIdx.x, tid = threadIdx.x;
  const float* p = spart + ((size_t)bc * DLX + tid) * 12;
  float s = 0.0f;
  #pragma unroll
  for (int j = 0; j < 12; j++) s += p[j];
  __shared__ float red[256];
  red[tid] = s;
  __syncthreads();
  for (int off = 128; off > 0; off >>= 1){
    if (tid < off) red[tid] += red[tid + off];
    __syncthreads();
  }
  if (tid == 0) out[bc] = red[0] + 256.0f * b2[0];
}

extern "C" void kernel_launch(void* const* d_in, const int* in_sizes, int n_in,
                              void* d_out, int out_size, void* d_ws, size_t ws_size,
                              hipStream_t stream){
  const float* xs = (const float*)d_in[0];
  const float* ys = (const float*)d_in[1];
  const float* W0 = (const float*)d_in[2];
  const float* b0 = (const float*)d_in[3];
  const float* W1 = (const float*)d_in[4];
  const float* b1 = (const float*)d_in[5];
  const float* W2 = (const float*)d_in[6];
  const float* b2 = (const float*)d_in[7];
  float* out = (float*)d_out;

  char* wsp = (char*)d_ws;
  size_t off = 0;
  auto alloc = [&](size_t bytes)->void*{
    void* p = wsp + off;
    off += (bytes + 255) & ~(size_t)255;
    return p;
  };
  // adjacency groups for 32-bit B-deltas: (ys16, W0yf), (xs16, W0xf), (H0, W1f)
  int* widx        = (int*)alloc((size_t)NTOK * 4);
  _Float16* ys16   = (_Float16*)alloc((size_t)NBC * DLY * DD * 2);   // 201 MB
  _Float16* W0yf   = (_Float16*)alloc((size_t)DH0 * DD * 2);
  _Float16* xs16   = (_Float16*)alloc((size_t)DB * DLX * DD * 2);
  _Float16* W0xf   = (_Float16*)alloc((size_t)DH0 * DD * 2);
  _Float16* X0h    = (_Float16*)alloc((size_t)DB * DLX * DH0 * 2);   // 6.3 MB
  float* spart     = (float*)alloc((size_t)NTOK * 12 * 4);           // 6.3 MB
  _Float16* H0     = (_Float16*)alloc((size_t)NTOK * DH0 * 2);       // 402 MB
  _Float16* W1f    = (_Float16*)alloc((size_t)DH1 * DH0 * 2);

  unsigned d0 = (unsigned)(W0xf - xs16);
  unsigned d1 = (unsigned)(W0yf - ys16);
  unsigned d2 = (unsigned)(W1f - H0);

  k_cvt16<<<dim3(576),  256, 0, stream>>>(W0, DH0, 0,  DH0, DD, W0xf);
  k_cvt16<<<dim3(576),  256, 0, stream>>>(W0, DH0, DD, DH0, DD, W0yf);
  k_cvt16<<<dim3(576),  256, 0, stream>>>(W1, DH0, 0,  DH1, DH0, W1f);
  k_cvt16<<<dim3(768),  256, 0, stream>>>(xs, DD, 0, DB*DLX, DD, xs16);
  k_scores4<<<dim3(NBC), 1024, 0, stream>>>(xs16, ys, xs, ys16, widx);
  k_gemm16<0><<<dim3(6, 16),   512, 0, stream>>>(xs16, d0, nullptr, nullptr, b0, nullptr, nullptr, X0h);
  k_gemm16<1><<<dim3(6, 1024), 512, 0, stream>>>(ys16, d1, widx, X0h, nullptr, nullptr, nullptr, H0);
  k_gemm16<2><<<dim3(3, 1024), 512, 0, stream>>>(H0, d2, nullptr, nullptr, b1, W2, spart, nullptr);
  k_reduce<<<NBC, 256, 0, stream>>>(spart, b2, out);
}